// Round 10
// baseline (681.365 us; speedup 1.0000x reference)
//
#include <hip/hip_runtime.h>
#include <hip/hip_cooperative_groups.h>
#include <stdint.h>

namespace cg = cooperative_groups;

#define D 128
#define EPB 4096   // edges per histogram/scatter block
#define CSZ 128    // nodes per cluster (cluster = dst >> 7)

typedef __bf16 bf16x8 __attribute__((ext_vector_type(8)));
typedef float f32x4 __attribute__((ext_vector_type(4)));

__device__ inline float bf2f(unsigned short u) {
    return __uint_as_float((unsigned)u << 16);
}
__device__ inline unsigned short f2bf(float f) {
    unsigned u = __float_as_uint(f);
    return (unsigned short)((u + 0x7FFF + ((u >> 16) & 1)) >> 16);  // RNE
}

struct Params {
    const float* x; const int* ei; const float* ew;
    const float* W1; const float* b1; const float* W2; const float* b2;
    float* out;
    int N, E, C, B1n, total, gb, hb, sb, G;
    unsigned short *Wt1, *Wt2;
    unsigned int* bh; int* ebase; int* bsums;
    float* dinv; int* cnt; int* rowstart;
    int2* brec; int2* erec;
    unsigned short *Hbuf, *Abuf;
};

// ================= phase bodies (shared by coop + fallback paths) =================

__device__ inline void dev_prep(int which, const Params& p) {
    const float* W = (which == 0) ? p.W1 : p.W2;
    unsigned short* Wt = (which == 0) ? p.Wt1 : p.Wt2;
    for (int i = threadIdx.x; i < 2048; i += 256) {
        int nn = i >> 4;
        int kc = (i & 15) << 3;
        ushort4 o0, o1;
        o0.x = f2bf(W[(kc + 0) * 128 + nn]); o0.y = f2bf(W[(kc + 1) * 128 + nn]);
        o0.z = f2bf(W[(kc + 2) * 128 + nn]); o0.w = f2bf(W[(kc + 3) * 128 + nn]);
        o1.x = f2bf(W[(kc + 4) * 128 + nn]); o1.y = f2bf(W[(kc + 5) * 128 + nn]);
        o1.z = f2bf(W[(kc + 6) * 128 + nn]); o1.w = f2bf(W[(kc + 7) * 128 + nn]);
        *(ushort4*)(Wt + nn * 128 + kc) = o0;
        *(ushort4*)(Wt + nn * 128 + kc + 4) = o1;
    }
}

__device__ inline void dev_hist(int b, const Params& p, unsigned int* hist) {
    for (int i = threadIdx.x; i < p.C; i += 256) hist[i] = 0;
    __syncthreads();
    const int base = b * EPB + threadIdx.x;
#pragma unroll
    for (int k = 0; k < EPB / 256; ++k) {
        int e = base + k * 256;
        if (e < p.E) atomicAdd(&hist[((unsigned)p.ei[p.E + e]) >> 7], 1u);
    }
    __syncthreads();
    for (int i = threadIdx.x; i < p.C; i += 256) p.bh[(size_t)b * p.C + i] = hist[i];
}

__device__ inline void dev_scanA(int blk, const Params& p, int* tmp) {
    const int tid = threadIdx.x;
    const int i = blk * 256 + tid;
    int v = 0;
    if (i < p.total) {
        int c = i / p.B1n;
        int b = i - c * p.B1n;
        v = (int)p.bh[(size_t)b * p.C + c];
    }
    tmp[tid] = v;
    __syncthreads();
    for (int off = 1; off < 256; off <<= 1) {
        int t = (tid >= off) ? tmp[tid - off] : 0;
        __syncthreads();
        tmp[tid] += t;
        __syncthreads();
    }
    if (i < p.total) p.ebase[i] = tmp[tid] - v;
    if (tid == 255) p.bsums[blk] = tmp[255];
}

__device__ inline void dev_scanB(int blk, const Params& p, int* sred) {
    const int tid = threadIdx.x;
    int v = (tid < blk) ? p.bsums[tid] : 0;
#pragma unroll
    for (int off = 32; off; off >>= 1) v += __shfl_down(v, off);
    if ((tid & 63) == 0) sred[tid >> 6] = v;
    __syncthreads();
    int tot = sred[0] + sred[1] + sred[2] + sred[3];
    int i = blk * 256 + tid;
    if (i < p.total) p.ebase[i] += tot;
}

__device__ inline void dev_scat(int b, const Params& p, unsigned int* cur) {
    for (int i = threadIdx.x; i < p.C; i += 256) cur[i] = 0;
    __syncthreads();
    const int base = b * EPB + threadIdx.x;
#pragma unroll
    for (int k = 0; k < EPB / 256; ++k) {
        int e = base + k * 256;
        if (e < p.E) {
            int s = p.ei[e];
            unsigned d = (unsigned)p.ei[p.E + e];
            float w = p.ew[e];
            int c = d >> 7;
            unsigned r = atomicAdd(&cur[c], 1u);
            int pos = p.ebase[c * p.B1n + b] + (int)r;
            p.brec[pos] = make_int2((int)((d << 16) | (unsigned)s), __float_as_int(w));
        }
    }
}

__device__ inline void dev_cbuild(int c, const Params& p, unsigned int* a) {
    unsigned int* hcnt = a;
    unsigned int* hdeg = a + CSZ;
    unsigned int* lsc  = a + 2 * CSZ;
    unsigned int* curs = a + 3 * CSZ;
    const int tid = threadIdx.x;
    const int cs = p.ebase[c * p.B1n];
    const int ce = (c + 1 < p.C) ? p.ebase[(c + 1) * p.B1n] : p.E;
    if (tid < CSZ) { hcnt[tid] = 0; hdeg[tid] = 0; }
    __syncthreads();
    for (int i = cs + tid; i < ce; i += 256) {
        int2 r = p.brec[i];
        int local = (int)(((unsigned)r.x) >> 16) & (CSZ - 1);
        atomicAdd(&hcnt[local], 1u);
        atomicAdd(&hdeg[local], (unsigned)(__int_as_float(r.y) * 16777216.0f));
    }
    __syncthreads();
    if (tid < CSZ) lsc[tid] = hcnt[tid];
    __syncthreads();
    for (int off = 1; off < CSZ; off <<= 1) {
        unsigned t = (tid < CSZ && tid >= off) ? lsc[tid - off] : 0u;
        __syncthreads();
        if (tid < CSZ) lsc[tid] += t;
        __syncthreads();
    }
    if (tid < CSZ) {
        unsigned excl = lsc[tid] - hcnt[tid];
        curs[tid] = excl;
        int node = c * CSZ + tid;
        if (node < p.N) {
            p.rowstart[node] = cs + (int)excl;
            p.cnt[node] = (int)hcnt[tid];
            float deg = 1.0f + (float)hdeg[tid] * (1.0f / 16777216.0f);
            p.dinv[node] = rsqrtf(deg);
        }
    }
    __syncthreads();
    for (int i = cs + tid; i < ce; i += 256) {
        int2 r = p.brec[i];
        int local = (int)(((unsigned)r.x) >> 16) & (CSZ - 1);
        unsigned rk = atomicAdd(&curs[local], 1u);
        p.erec[cs + (int)rk] = make_int2(r.x & 0xFFFF, r.y);   // (src, ew)
    }
}

// ---------------- MFMA GEMM body (R6-verified): direct-global A/B frags ----------------
template <bool IN_BF16>
__device__ inline void mfma_body(unsigned short* sE,
                                 const void* __restrict__ Xv,
                                 const unsigned short* __restrict__ Wt,
                                 unsigned short* __restrict__ H, int n, int blk) {
    const int tid = threadIdx.x;
    const int row0 = blk * 64;
    const int lane = tid & 63;
    const int wv = tid >> 6;
    const int qm = lane & 15;
    const int quad = lane >> 4;

    const int arow = row0 + wv * 16 + qm;
    const int ar = (arow < n) ? arow : (n - 1);

    f32x4 acc[8];
#pragma unroll
    for (int i = 0; i < 8; ++i) acc[i] = (f32x4){0.f, 0.f, 0.f, 0.f};

#pragma unroll
    for (int kb = 0; kb < 4; ++kb) {
        const int koff = kb * 32 + quad * 8;
        bf16x8 a;
        if (IN_BF16) {
            a = *(const bf16x8*)((const unsigned short*)Xv + (size_t)ar * 128 + koff);
        } else {
            const float* Xf = (const float*)Xv + (size_t)ar * 128 + koff;
            float4 v0 = *(const float4*)(Xf);
            float4 v1 = *(const float4*)(Xf + 4);
            union { bf16x8 v; ushort4 u[2]; } cv;
            cv.u[0].x = f2bf(v0.x); cv.u[0].y = f2bf(v0.y);
            cv.u[0].z = f2bf(v0.z); cv.u[0].w = f2bf(v0.w);
            cv.u[1].x = f2bf(v1.x); cv.u[1].y = f2bf(v1.y);
            cv.u[1].z = f2bf(v1.z); cv.u[1].w = f2bf(v1.w);
            a = cv.v;
        }
#pragma unroll
        for (int n0 = 0; n0 < 8; ++n0) {
            bf16x8 b = *(const bf16x8*)(Wt + (n0 * 16 + qm) * 128 + koff);
            acc[n0] = __builtin_amdgcn_mfma_f32_16x16x32_bf16(a, b, acc[n0], 0, 0, 0);
        }
    }

#pragma unroll
    for (int n0 = 0; n0 < 8; ++n0)
#pragma unroll
        for (int r = 0; r < 4; ++r)
            sE[(wv * 16 + quad * 4 + r) * 136 + n0 * 16 + qm] = f2bf(acc[n0][r]);
    __syncthreads();

    const int row_in = lane >> 2;
    const int c0 = (lane & 3) * 4;
    const int grow = row0 + wv * 16 + row_in;
    if (grow < n) {
#pragma unroll
        for (int j = 0; j < 4; ++j)
            *(int4*)(H + (size_t)grow * 128 + (c0 + j) * 8) =
                *(const int4*)(&sE[(wv * 16 + row_in) * 136 + (c0 + j) * 8]);
    }
}

// ---------------- gather body: OUT[d] = b + dinv[d]*(dinv[d]*H[d] + sum (dinv[s]*ew)*H[s]) ----------------
template <bool OUT_BF16>
__device__ inline void gather_body(const Params& p, const ushort4* __restrict__ H4,
                                   const float4* __restrict__ bias4,
                                   void* __restrict__ OUTv, int g) {
    const int lane = threadIdx.x & 31;
    const int node = g * 8 + (threadIdx.x >> 5);
    if (node >= p.N) return;
    const int start = p.rowstart[node];
    const int m = p.cnt[node];
    const float di = p.dinv[node];

    float4 b = bias4[lane];
    ushort4 h = H4[(size_t)node * 32 + lane];
    float ax = di * bf2f(h.x);
    float ay = di * bf2f(h.y);
    float az = di * bf2f(h.z);
    float aw = di * bf2f(h.w);

    int j = 0;
    for (; j + 4 <= m; j += 4) {
        const int base = start + j;
        int2 e0 = p.erec[base + 0], e1 = p.erec[base + 1];
        int2 e2 = p.erec[base + 2], e3 = p.erec[base + 3];
        float w0 = p.dinv[e0.x] * __int_as_float(e0.y);
        float w1 = p.dinv[e1.x] * __int_as_float(e1.y);
        float w2 = p.dinv[e2.x] * __int_as_float(e2.y);
        float w3 = p.dinv[e3.x] * __int_as_float(e3.y);
        ushort4 v0 = H4[(size_t)e0.x * 32 + lane];
        ushort4 v1 = H4[(size_t)e1.x * 32 + lane];
        ushort4 v2 = H4[(size_t)e2.x * 32 + lane];
        ushort4 v3 = H4[(size_t)e3.x * 32 + lane];
        ax += w0 * bf2f(v0.x); ay += w0 * bf2f(v0.y); az += w0 * bf2f(v0.z); aw += w0 * bf2f(v0.w);
        ax += w1 * bf2f(v1.x); ay += w1 * bf2f(v1.y); az += w1 * bf2f(v1.z); aw += w1 * bf2f(v1.w);
        ax += w2 * bf2f(v2.x); ay += w2 * bf2f(v2.y); az += w2 * bf2f(v2.z); aw += w2 * bf2f(v2.w);
        ax += w3 * bf2f(v3.x); ay += w3 * bf2f(v3.y); az += w3 * bf2f(v3.z); aw += w3 * bf2f(v3.w);
    }
    for (; j < m; ++j) {
        int2 er = p.erec[start + j];
        float w = p.dinv[er.x] * __int_as_float(er.y);
        ushort4 v = H4[(size_t)er.x * 32 + lane];
        ax += w * bf2f(v.x); ay += w * bf2f(v.y); az += w * bf2f(v.z); aw += w * bf2f(v.w);
    }
    ax = b.x + di * ax; ay = b.y + di * ay;
    az = b.z + di * az; aw = b.w + di * aw;
    if (OUT_BF16) {
        ushort4 o;
        o.x = f2bf(fmaxf(ax, 0.f)); o.y = f2bf(fmaxf(ay, 0.f));
        o.z = f2bf(fmaxf(az, 0.f)); o.w = f2bf(fmaxf(aw, 0.f));
        ((ushort4*)OUTv)[(size_t)node * 32 + lane] = o;
    } else {
        float4 o; o.x = ax; o.y = ay; o.z = az; o.w = aw;
        ((float4*)OUTv)[(size_t)node * 32 + lane] = o;
    }
}

// ================= cooperative single-kernel pipeline (grid-stride phases) =================
__global__ __launch_bounds__(256, 4) void k_all(Params p) {
    cg::grid_group grid = cg::this_grid();
    __shared__ __align__(16) char arena[64 * 136 * 2];
    const int bid = blockIdx.x;

    for (int w = bid; w < 2 + p.B1n; w += p.G) {
        if (w < 2) dev_prep(w, p); else dev_hist(w - 2, p, (unsigned int*)arena);
        __syncthreads();
    }
    grid.sync();
    for (int w = bid; w < p.gb + p.sb; w += p.G) {
        if (w < p.gb) mfma_body<false>((unsigned short*)arena, (const void*)p.x, p.Wt1, p.Hbuf, p.N, w);
        else dev_scanA(w - p.gb, p, (int*)arena);
        __syncthreads();
    }
    grid.sync();
    for (int w = bid; w < p.sb; w += p.G) { dev_scanB(w, p, (int*)arena); __syncthreads(); }
    grid.sync();
    for (int w = bid; w < p.B1n; w += p.G) { dev_scat(w, p, (unsigned int*)arena); __syncthreads(); }
    grid.sync();
    for (int w = bid; w < p.C; w += p.G) { dev_cbuild(w, p, (unsigned int*)arena); __syncthreads(); }
    grid.sync();
    for (int g = bid; g < p.hb; g += p.G)
        gather_body<true>(p, (const ushort4*)p.Hbuf, (const float4*)p.b1, (void*)p.Abuf, g);
    grid.sync();
    for (int w = bid; w < p.gb; w += p.G) {
        mfma_body<true>((unsigned short*)arena, (const void*)p.Abuf, p.Wt2, p.Hbuf, p.N, w);
        __syncthreads();
    }
    grid.sync();
    for (int g = bid; g < p.hb; g += p.G)
        gather_body<false>(p, (const ushort4*)p.Hbuf, (const float4*)p.b2, (void*)p.out, g);
}

// ================= fallback: 8 plain kernels sharing the same bodies =================
__global__ __launch_bounds__(256, 4) void k_f0(Params p) {
    __shared__ __align__(16) char arena[64 * 136 * 2];
    if (blockIdx.x < 2) dev_prep(blockIdx.x, p);
    else dev_hist(blockIdx.x - 2, p, (unsigned int*)arena);
}
__global__ __launch_bounds__(256, 4) void k_f1(Params p) {
    __shared__ __align__(16) char arena[64 * 136 * 2];
    if ((int)blockIdx.x < p.gb) mfma_body<false>((unsigned short*)arena, (const void*)p.x, p.Wt1, p.Hbuf, p.N, blockIdx.x);
    else dev_scanA(blockIdx.x - p.gb, p, (int*)arena);
}
__global__ __launch_bounds__(256) void k_f2(Params p) {
    __shared__ int sred[4];
    dev_scanB(blockIdx.x, p, sred);
}
__global__ __launch_bounds__(256) void k_f3(Params p) {
    __shared__ unsigned int cur[512];
    dev_scat(blockIdx.x, p, cur);
}
__global__ __launch_bounds__(256) void k_f4(Params p) {
    __shared__ unsigned int a[4 * CSZ];
    dev_cbuild(blockIdx.x, p, a);
}
__global__ __launch_bounds__(256) void k_f5(Params p) {
    gather_body<true>(p, (const ushort4*)p.Hbuf, (const float4*)p.b1, (void*)p.Abuf, blockIdx.x);
}
__global__ __launch_bounds__(256, 4) void k_f6(Params p) {
    __shared__ __align__(16) char arena[64 * 136 * 2];
    mfma_body<true>((unsigned short*)arena, (const void*)p.Abuf, p.Wt2, p.Hbuf, p.N, blockIdx.x);
}
__global__ __launch_bounds__(256) void k_f7(Params p) {
    gather_body<false>(p, (const ushort4*)p.Hbuf, (const float4*)p.b2, (void*)p.out, blockIdx.x);
}

extern "C" void kernel_launch(void* const* d_in, const int* in_sizes, int n_in,
                              void* d_out, int out_size, void* d_ws, size_t ws_size,
                              hipStream_t stream) {
    Params p;
    p.x  = (const float*)d_in[0];
    p.ei = (const int*)d_in[1];
    p.ew = (const float*)d_in[2];
    p.W1 = (const float*)d_in[3];
    p.b1 = (const float*)d_in[4];
    p.W2 = (const float*)d_in[5];
    p.b2 = (const float*)d_in[6];
    p.out = (float*)d_out;

    p.N = in_sizes[0] / D;
    p.E = in_sizes[2];
    p.C = (p.N + CSZ - 1) / CSZ;
    p.B1n = (p.E + EPB - 1) / EPB;
    p.total = p.C * p.B1n;
    p.sb = (p.total + 255) / 256;
    p.gb = (p.N + 63) / 64;
    p.hb = (p.N + 7) / 8;

    char* w = (char*)d_ws;
    auto alloc = [&](size_t bytes) {
        void* r = (void*)w;
        w += (bytes + 255) & ~(size_t)255;
        return r;
    };
    p.bh       = (unsigned int*)alloc((size_t)p.total * 4);
    p.ebase    = (int*)alloc((size_t)p.total * 4);
    p.bsums    = (int*)alloc(1024 * 4);
    p.dinv     = (float*)alloc((size_t)p.N * 4);
    p.cnt      = (int*)alloc((size_t)p.N * 4);
    p.rowstart = (int*)alloc((size_t)p.N * 4);
    p.brec     = (int2*)alloc((size_t)p.E * 8);
    p.erec     = (int2*)alloc((size_t)p.E * 8);
    p.Hbuf     = (unsigned short*)alloc((size_t)p.N * D * 2);
    p.Abuf     = (unsigned short*)alloc((size_t)p.N * D * 2);
    p.Wt1      = (unsigned short*)alloc(128 * 128 * 2);
    p.Wt2      = (unsigned short*)alloc(128 * 128 * 2);

    // size cooperative grid from the runtime's own occupancy model
    int dev = 0;
    (void)hipGetDevice(&dev);
    int numCU = 0;
    (void)hipDeviceGetAttribute(&numCU, hipDeviceAttributeMultiprocessorCount, dev);
    int maxB = 0;
    hipError_t oe = hipOccupancyMaxActiveBlocksPerMultiprocessor(&maxB, (const void*)k_all, 256, 0);

    bool coop = (oe == hipSuccess && maxB > 0 && numCU > 0);
    hipError_t le = hipErrorUnknown;
    if (coop) {
        long g = (long)numCU * maxB;
        p.G = (g > 1008) ? 1008 : (int)g;
        if (p.G < 64) coop = false;
    }
    if (coop) {
        void* args[] = { &p };
        le = hipLaunchCooperativeKernel((const void*)k_all, dim3(p.G), dim3(256), args, 0, stream);
    }
    if (!coop || le != hipSuccess) {
        (void)hipGetLastError();   // clear any sticky error from the failed coop attempt
        k_f0<<<2 + p.B1n, 256, 0, stream>>>(p);
        k_f1<<<p.gb + p.sb, 256, 0, stream>>>(p);
        k_f2<<<p.sb, 256, 0, stream>>>(p);
        k_f3<<<p.B1n, 256, 0, stream>>>(p);
        k_f4<<<p.C, 256, 0, stream>>>(p);
        k_f5<<<p.hb, 256, 0, stream>>>(p);
        k_f6<<<p.gb, 256, 0, stream>>>(p);
        k_f7<<<p.hb, 256, 0, stream>>>(p);
    }
}

// Round 11
// 216.564 us; speedup vs baseline: 3.1462x; 3.1462x over previous
//
#include <hip/hip_runtime.h>
#include <stdint.h>

#define D 128
#define EPB 4096   // edges per histogram/scatter block
#define CSZ 128    // nodes per cluster (cluster = dst >> 7)

typedef __bf16 bf16x8 __attribute__((ext_vector_type(8)));
typedef float f32x4 __attribute__((ext_vector_type(4)));

__device__ inline float bf2f(unsigned short u) {
    return __uint_as_float((unsigned)u << 16);
}
__device__ inline unsigned short f2bf(float f) {
    unsigned u = __float_as_uint(f);
    return (unsigned short)((u + 0x7FFF + ((u >> 16) & 1)) >> 16);  // RNE
}

struct Params {
    const float* x; const int* ei; const float* ew;
    const float* W1; const float* b1; const float* W2; const float* b2;
    float* out;
    int N, E, C, B1n, total, gb, hb, sb;
    unsigned short *Wt1, *Wt2;
    unsigned int* bh; int* ebase; int* bsums;
    float* dinv; int* cnt; int* rowstart;
    int2* brec; int2* erec;
    unsigned short *Hbuf, *Abuf;
};

// ================= phase bodies =================

__device__ inline void dev_prep(int which, const Params& p) {
    const float* W = (which == 0) ? p.W1 : p.W2;
    unsigned short* Wt = (which == 0) ? p.Wt1 : p.Wt2;
    for (int i = threadIdx.x; i < 2048; i += 256) {
        int nn = i >> 4;
        int kc = (i & 15) << 3;
        ushort4 o0, o1;
        o0.x = f2bf(W[(kc + 0) * 128 + nn]); o0.y = f2bf(W[(kc + 1) * 128 + nn]);
        o0.z = f2bf(W[(kc + 2) * 128 + nn]); o0.w = f2bf(W[(kc + 3) * 128 + nn]);
        o1.x = f2bf(W[(kc + 4) * 128 + nn]); o1.y = f2bf(W[(kc + 5) * 128 + nn]);
        o1.z = f2bf(W[(kc + 6) * 128 + nn]); o1.w = f2bf(W[(kc + 7) * 128 + nn]);
        *(ushort4*)(Wt + nn * 128 + kc) = o0;
        *(ushort4*)(Wt + nn * 128 + kc + 4) = o1;
    }
}

__device__ inline void dev_hist(int b, const Params& p, unsigned int* hist) {
    for (int i = threadIdx.x; i < p.C; i += 256) hist[i] = 0;
    __syncthreads();
    const int base = b * EPB + threadIdx.x;
#pragma unroll
    for (int k = 0; k < EPB / 256; ++k) {
        int e = base + k * 256;
        if (e < p.E) atomicAdd(&hist[((unsigned)p.ei[p.E + e]) >> 7], 1u);
    }
    __syncthreads();
    for (int i = threadIdx.x; i < p.C; i += 256) p.bh[(size_t)b * p.C + i] = hist[i];
}

__device__ inline void dev_scanA(int blk, const Params& p, int* tmp) {
    const int tid = threadIdx.x;
    const int i = blk * 256 + tid;
    int v = 0;
    if (i < p.total) {
        int c = i / p.B1n;
        int b = i - c * p.B1n;
        v = (int)p.bh[(size_t)b * p.C + c];
    }
    tmp[tid] = v;
    __syncthreads();
    for (int off = 1; off < 256; off <<= 1) {
        int t = (tid >= off) ? tmp[tid - off] : 0;
        __syncthreads();
        tmp[tid] += t;
        __syncthreads();
    }
    if (i < p.total) p.ebase[i] = tmp[tid] - v;
    if (tid == 255) p.bsums[blk] = tmp[255];
}

__device__ inline void dev_scanB(int blk, const Params& p, int* sred) {
    const int tid = threadIdx.x;
    int v = (tid < blk) ? p.bsums[tid] : 0;
#pragma unroll
    for (int off = 32; off; off >>= 1) v += __shfl_down(v, off);
    if ((tid & 63) == 0) sred[tid >> 6] = v;
    __syncthreads();
    int tot = sred[0] + sred[1] + sred[2] + sred[3];
    int i = blk * 256 + tid;
    if (i < p.total) p.ebase[i] += tot;
}

__device__ inline void dev_scat(int b, const Params& p, unsigned int* cur) {
    for (int i = threadIdx.x; i < p.C; i += 256) cur[i] = 0;
    __syncthreads();
    const int base = b * EPB + threadIdx.x;
#pragma unroll
    for (int k = 0; k < EPB / 256; ++k) {
        int e = base + k * 256;
        if (e < p.E) {
            int s = p.ei[e];
            unsigned d = (unsigned)p.ei[p.E + e];
            float w = p.ew[e];
            int c = d >> 7;
            unsigned r = atomicAdd(&cur[c], 1u);
            int pos = p.ebase[c * p.B1n + b] + (int)r;
            p.brec[pos] = make_int2((int)((d << 16) | (unsigned)s), __float_as_int(w));
        }
    }
}

__device__ inline void dev_cbuild(int c, const Params& p, unsigned int* a) {
    unsigned int* hcnt = a;
    unsigned int* hdeg = a + CSZ;
    unsigned int* lsc  = a + 2 * CSZ;
    unsigned int* curs = a + 3 * CSZ;
    const int tid = threadIdx.x;
    const int cs = p.ebase[c * p.B1n];
    const int ce = (c + 1 < p.C) ? p.ebase[(c + 1) * p.B1n] : p.E;
    if (tid < CSZ) { hcnt[tid] = 0; hdeg[tid] = 0; }
    __syncthreads();
    for (int i = cs + tid; i < ce; i += 256) {
        int2 r = p.brec[i];
        int local = (int)(((unsigned)r.x) >> 16) & (CSZ - 1);
        atomicAdd(&hcnt[local], 1u);
        atomicAdd(&hdeg[local], (unsigned)(__int_as_float(r.y) * 16777216.0f));
    }
    __syncthreads();
    if (tid < CSZ) lsc[tid] = hcnt[tid];
    __syncthreads();
    for (int off = 1; off < CSZ; off <<= 1) {
        unsigned t = (tid < CSZ && tid >= off) ? lsc[tid - off] : 0u;
        __syncthreads();
        if (tid < CSZ) lsc[tid] += t;
        __syncthreads();
    }
    if (tid < CSZ) {
        unsigned excl = lsc[tid] - hcnt[tid];
        curs[tid] = excl;
        int node = c * CSZ + tid;
        if (node < p.N) {
            p.rowstart[node] = cs + (int)excl;
            p.cnt[node] = (int)hcnt[tid];
            float deg = 1.0f + (float)hdeg[tid] * (1.0f / 16777216.0f);
            p.dinv[node] = rsqrtf(deg);
        }
    }
    __syncthreads();
    for (int i = cs + tid; i < ce; i += 256) {
        int2 r = p.brec[i];
        int local = (int)(((unsigned)r.x) >> 16) & (CSZ - 1);
        unsigned rk = atomicAdd(&curs[local], 1u);
        p.erec[cs + (int)rk] = make_int2(r.x & 0xFFFF, r.y);   // (src, ew)
    }
}

// ---------------- MFMA GEMM body (R6-verified): direct-global A/B frags ----------------
template <bool IN_BF16>
__device__ inline void mfma_body(unsigned short* sE,
                                 const void* __restrict__ Xv,
                                 const unsigned short* __restrict__ Wt,
                                 unsigned short* __restrict__ H, int n, int blk) {
    const int tid = threadIdx.x;
    const int row0 = blk * 64;
    const int lane = tid & 63;
    const int wv = tid >> 6;
    const int qm = lane & 15;
    const int quad = lane >> 4;

    const int arow = row0 + wv * 16 + qm;
    const int ar = (arow < n) ? arow : (n - 1);

    f32x4 acc[8];
#pragma unroll
    for (int i = 0; i < 8; ++i) acc[i] = (f32x4){0.f, 0.f, 0.f, 0.f};

#pragma unroll
    for (int kb = 0; kb < 4; ++kb) {
        const int koff = kb * 32 + quad * 8;
        bf16x8 a;
        if (IN_BF16) {
            a = *(const bf16x8*)((const unsigned short*)Xv + (size_t)ar * 128 + koff);
        } else {
            const float* Xf = (const float*)Xv + (size_t)ar * 128 + koff;
            float4 v0 = *(const float4*)(Xf);
            float4 v1 = *(const float4*)(Xf + 4);
            union { bf16x8 v; ushort4 u[2]; } cv;
            cv.u[0].x = f2bf(v0.x); cv.u[0].y = f2bf(v0.y);
            cv.u[0].z = f2bf(v0.z); cv.u[0].w = f2bf(v0.w);
            cv.u[1].x = f2bf(v1.x); cv.u[1].y = f2bf(v1.y);
            cv.u[1].z = f2bf(v1.z); cv.u[1].w = f2bf(v1.w);
            a = cv.v;
        }
#pragma unroll
        for (int n0 = 0; n0 < 8; ++n0) {
            bf16x8 b = *(const bf16x8*)(Wt + (n0 * 16 + qm) * 128 + koff);
            acc[n0] = __builtin_amdgcn_mfma_f32_16x16x32_bf16(a, b, acc[n0], 0, 0, 0);
        }
    }

#pragma unroll
    for (int n0 = 0; n0 < 8; ++n0)
#pragma unroll
        for (int r = 0; r < 4; ++r)
            sE[(wv * 16 + quad * 4 + r) * 136 + n0 * 16 + qm] = f2bf(acc[n0][r]);
    __syncthreads();

    const int row_in = lane >> 2;
    const int c0 = (lane & 3) * 4;
    const int grow = row0 + wv * 16 + row_in;
    if (grow < n) {
#pragma unroll
        for (int j = 0; j < 4; ++j)
            *(int4*)(H + (size_t)grow * 128 + (c0 + j) * 8) =
                *(const int4*)(&sE[(wv * 16 + row_in) * 136 + (c0 + j) * 8]);
    }
}

// ---------------- gather body: OUT[d] = b + dinv[d]*(dinv[d]*H[d] + sum (dinv[s]*ew)*H[s]) ----------------
template <bool OUT_BF16>
__device__ inline void gather_body(const Params& p, const ushort4* __restrict__ H4,
                                   const float4* __restrict__ bias4,
                                   void* __restrict__ OUTv, int g) {
    const int lane = threadIdx.x & 31;
    const int node = g * 8 + (threadIdx.x >> 5);
    if (node >= p.N) return;
    const int start = p.rowstart[node];
    const int m = p.cnt[node];
    const float di = p.dinv[node];

    float4 b = bias4[lane];
    ushort4 h = H4[(size_t)node * 32 + lane];
    float ax = di * bf2f(h.x);
    float ay = di * bf2f(h.y);
    float az = di * bf2f(h.z);
    float aw = di * bf2f(h.w);

    int j = 0;
    for (; j + 4 <= m; j += 4) {
        const int base = start + j;
        int2 e0 = p.erec[base + 0], e1 = p.erec[base + 1];
        int2 e2 = p.erec[base + 2], e3 = p.erec[base + 3];
        float w0 = p.dinv[e0.x] * __int_as_float(e0.y);
        float w1 = p.dinv[e1.x] * __int_as_float(e1.y);
        float w2 = p.dinv[e2.x] * __int_as_float(e2.y);
        float w3 = p.dinv[e3.x] * __int_as_float(e3.y);
        ushort4 v0 = H4[(size_t)e0.x * 32 + lane];
        ushort4 v1 = H4[(size_t)e1.x * 32 + lane];
        ushort4 v2 = H4[(size_t)e2.x * 32 + lane];
        ushort4 v3 = H4[(size_t)e3.x * 32 + lane];
        ax += w0 * bf2f(v0.x); ay += w0 * bf2f(v0.y); az += w0 * bf2f(v0.z); aw += w0 * bf2f(v0.w);
        ax += w1 * bf2f(v1.x); ay += w1 * bf2f(v1.y); az += w1 * bf2f(v1.z); aw += w1 * bf2f(v1.w);
        ax += w2 * bf2f(v2.x); ay += w2 * bf2f(v2.y); az += w2 * bf2f(v2.z); aw += w2 * bf2f(v2.w);
        ax += w3 * bf2f(v3.x); ay += w3 * bf2f(v3.y); az += w3 * bf2f(v3.z); aw += w3 * bf2f(v3.w);
    }
    for (; j < m; ++j) {
        int2 er = p.erec[start + j];
        float w = p.dinv[er.x] * __int_as_float(er.y);
        ushort4 v = H4[(size_t)er.x * 32 + lane];
        ax += w * bf2f(v.x); ay += w * bf2f(v.y); az += w * bf2f(v.z); aw += w * bf2f(v.w);
    }
    ax = b.x + di * ax; ay = b.y + di * ay;
    az = b.z + di * az; aw = b.w + di * aw;
    if (OUT_BF16) {
        ushort4 o;
        o.x = f2bf(fmaxf(ax, 0.f)); o.y = f2bf(fmaxf(ay, 0.f));
        o.z = f2bf(fmaxf(az, 0.f)); o.w = f2bf(fmaxf(aw, 0.f));
        ((ushort4*)OUTv)[(size_t)node * 32 + lane] = o;
    } else {
        float4 o; o.x = ax; o.y = ay; o.z = az; o.w = aw;
        ((float4*)OUTv)[(size_t)node * 32 + lane] = o;
    }
}

// ================= 8-kernel pipeline =================
__global__ __launch_bounds__(256, 4) void k_f0(Params p) {
    __shared__ __align__(16) char arena[64 * 136 * 2];
    if (blockIdx.x < 2) dev_prep(blockIdx.x, p);
    else dev_hist(blockIdx.x - 2, p, (unsigned int*)arena);
}
__global__ __launch_bounds__(256, 4) void k_f1(Params p) {
    __shared__ __align__(16) char arena[64 * 136 * 2];
    if ((int)blockIdx.x < p.gb) mfma_body<false>((unsigned short*)arena, (const void*)p.x, p.Wt1, p.Hbuf, p.N, blockIdx.x);
    else dev_scanA(blockIdx.x - p.gb, p, (int*)arena);
}
__global__ __launch_bounds__(256) void k_f2(Params p) {
    __shared__ int sred[4];
    dev_scanB(blockIdx.x, p, sred);
}
__global__ __launch_bounds__(256) void k_f3(Params p) {
    __shared__ unsigned int cur[512];
    dev_scat(blockIdx.x, p, cur);
}
__global__ __launch_bounds__(256) void k_f4(Params p) {
    __shared__ unsigned int a[4 * CSZ];
    dev_cbuild(blockIdx.x, p, a);
}
__global__ __launch_bounds__(256) void k_f5(Params p) {
    gather_body<true>(p, (const ushort4*)p.Hbuf, (const float4*)p.b1, (void*)p.Abuf, blockIdx.x);
}
__global__ __launch_bounds__(256, 4) void k_f6(Params p) {
    __shared__ __align__(16) char arena[64 * 136 * 2];
    mfma_body<true>((unsigned short*)arena, (const void*)p.Abuf, p.Wt2, p.Hbuf, p.N, blockIdx.x);
}
__global__ __launch_bounds__(256) void k_f7(Params p) {
    gather_body<false>(p, (const ushort4*)p.Hbuf, (const float4*)p.b2, (void*)p.out, blockIdx.x);
}

extern "C" void kernel_launch(void* const* d_in, const int* in_sizes, int n_in,
                              void* d_out, int out_size, void* d_ws, size_t ws_size,
                              hipStream_t stream) {
    Params p;
    p.x  = (const float*)d_in[0];
    p.ei = (const int*)d_in[1];
    p.ew = (const float*)d_in[2];
    p.W1 = (const float*)d_in[3];
    p.b1 = (const float*)d_in[4];
    p.W2 = (const float*)d_in[5];
    p.b2 = (const float*)d_in[6];
    p.out = (float*)d_out;

    p.N = in_sizes[0] / D;
    p.E = in_sizes[2];
    p.C = (p.N + CSZ - 1) / CSZ;
    p.B1n = (p.E + EPB - 1) / EPB;
    p.total = p.C * p.B1n;
    p.sb = (p.total + 255) / 256;
    p.gb = (p.N + 63) / 64;
    p.hb = (p.N + 7) / 8;

    char* w = (char*)d_ws;
    auto alloc = [&](size_t bytes) {
        void* r = (void*)w;
        w += (bytes + 255) & ~(size_t)255;
        return r;
    };
    p.bh       = (unsigned int*)alloc((size_t)p.total * 4);
    p.ebase    = (int*)alloc((size_t)p.total * 4);
    p.bsums    = (int*)alloc(1024 * 4);
    p.dinv     = (float*)alloc((size_t)p.N * 4);
    p.cnt      = (int*)alloc((size_t)p.N * 4);
    p.rowstart = (int*)alloc((size_t)p.N * 4);
    p.brec     = (int2*)alloc((size_t)p.E * 8);
    p.erec     = (int2*)alloc((size_t)p.E * 8);
    p.Hbuf     = (unsigned short*)alloc((size_t)p.N * D * 2);
    p.Abuf     = (unsigned short*)alloc((size_t)p.N * D * 2);
    p.Wt1      = (unsigned short*)alloc(128 * 128 * 2);
    p.Wt2      = (unsigned short*)alloc(128 * 128 * 2);

    k_f0<<<2 + p.B1n, 256, 0, stream>>>(p);
    k_f1<<<p.gb + p.sb, 256, 0, stream>>>(p);
    k_f2<<<p.sb, 256, 0, stream>>>(p);
    k_f3<<<p.B1n, 256, 0, stream>>>(p);
    k_f4<<<p.C, 256, 0, stream>>>(p);
    k_f5<<<p.hb, 256, 0, stream>>>(p);
    k_f6<<<p.gb, 256, 0, stream>>>(p);
    k_f7<<<p.hb, 256, 0, stream>>>(p);
}